// Round 2
// baseline (220.687 us; speedup 1.0000x reference)
//
#include <hip/hip_runtime.h>

#define SZ   256   // image size
#define NPTS 128   // points per batch
#define NB3  6     // bs * ncam = 2*3

// v_exp_f32 / v_log_f32: base-2 exp and log, single-instruction on gfx950.
#define EXP2F(x) __builtin_amdgcn_exp2f(x)
#define LOG2F(x) __builtin_amdgcn_logf(x)

// native 16-byte vector type (HIP's float4 is a class; the nontemporal
// builtin needs a real vector type)
typedef float v4f __attribute__((ext_vector_type(4)));

// Global normalization over all 6 camera values (jnp .mean()/.max() reduce the
// whole (2,3) array, not per-row).
__device__ __forceinline__ float norm6(const float* __restrict__ v, int idx) {
    float a0 = v[0], a1 = v[1], a2 = v[2], a3 = v[3], a4 = v[4], a5 = v[5];
    float mean = (a0 + a1 + a2 + a3 + a4 + a5) * (1.0f / 6.0f);
    float inv = 1.0f / mean;
    float b0 = a0 * inv, b1 = a1 * inv, b2 = a2 * inv;
    float b3 = a3 * inv, b4 = a4 * inv, b5 = a5 * inv;
    float d = fmaxf(fmaxf(fmaxf(fabsf(b0 - 1.f), fabsf(b1 - 1.f)),
                          fmaxf(fabsf(b2 - 1.f), fabsf(b3 - 1.f))),
                    fmaxf(fabsf(b4 - 1.f), fabsf(b5 - 1.f)));
    float sf = 0.2f / d;                 // d==0 -> inf -> takes 'vi' branch
    float vi = v[idx] * inv;
    return (sf < 1.0f) ? (vi - 1.0f) * sf + 1.0f : vi;
}

// blob = exp(-(dst*q)^e) = exp2(-exp2(e*log2(dst) + c2)),
//   c2 = e*log2(q) + log2(log2(e))
//
// Layout: 128 threads/block = 2 rows x 64 lanes; each thread owns 4
// consecutive x-pixels -> one 16B nontemporal store per plane
// (1 KB per wave-instruction; output is never re-read, keep it out of L2/L3).
__global__ __launch_bounds__(128) void render_kernel(
    const float* __restrict__ points,       // (2,3,128,2)
    const float* __restrict__ sigmas,       // (2,128)
    const float* __restrict__ exponents,    // (2,128)
    const float* __restrict__ intensities,  // (2,128)
    const float* __restrict__ cam_s,        // (2,3)
    const float* __restrict__ cam_e,        // (2,3)
    const float* __restrict__ cam_i,        // (2,3)
    float* __restrict__ masks,              // (6,256,256)
    float* __restrict__ blobs)              // (6,128,256,256)
{
    __shared__ float4 s_p[NPTS];   // px, py, e, c2
    __shared__ float  s_i[NPTS];   // intensity

    const int tid = threadIdx.x;                       // 0..127
    const int b3  = blockIdx.x >> 7;                   // [0,6)
    const int y   = ((blockIdx.x & 127) << 1) + (tid >> 6);  // row
    const int x   = (tid & 63) << 2;                   // first of 4 x-pixels

    {   // all 128 threads: one point each
        const int b = b3 / 3;
        const float cs = norm6(cam_s, b3);
        const float ce = norm6(cam_e, b3);
        const float ci = norm6(cam_i, b3);
        float px = points[(b3 * NPTS + tid) * 2 + 0];
        float py = points[(b3 * NPTS + tid) * 2 + 1];
        px = fminf(fmaxf((px - 128.0f) * (1.0f / 128.0f), -1.0f), 1.0f);
        py = fminf(fmaxf((py - 128.0f) * (1.0f / 128.0f), -1.0f), 1.0f);
        const float sg = sigmas[b * NPTS + tid] * cs;
        const float e  = exponents[b * NPTS + tid] * ce;
        const float q  = 1.0f / (2.0f * sg * sg);
        const float C  = 0.5287663729448977f;           // log2(log2(e))
        const float c2 = fmaf(e, LOG2F(q), C);
        s_p[tid] = make_float4(px, py, e, c2);
        s_i[tid] = intensities[b * NPTS + tid] * ci;
    }
    __syncthreads();

    const float gy  = -1.0f + (float)y * (2.0f / 255.0f);
    // exact same per-pixel numerics as the 1-px/thread version
    const float gx0 = -1.0f + (float)(x + 0) * (2.0f / 255.0f);
    const float gx1 = -1.0f + (float)(x + 1) * (2.0f / 255.0f);
    const float gx2 = -1.0f + (float)(x + 2) * (2.0f / 255.0f);
    const float gx3 = -1.0f + (float)(x + 3) * (2.0f / 255.0f);

    float m0 = 0.0f, m1 = 0.0f, m2 = 0.0f, m3 = 0.0f;
    v4f* bptr = (v4f*)(blobs + (size_t)b3 * NPTS * SZ * SZ
                             + (size_t)y * SZ + x);
    const size_t pstride = (SZ * SZ) / 4;   // plane stride in v4f units

    #pragma unroll 2
    for (int n = 0; n < NPTS; ++n) {
        const float4 p     = s_p[n];
        const float  inten = s_i[n];
        const float  dy    = gy - p.y;
        const float  dy2   = dy * dy;
        const float  d0 = gx0 - p.x, d1 = gx1 - p.x;
        const float  d2 = gx2 - p.x, d3 = gx3 - p.x;
        const float  u0 = fmaf(d0, d0, dy2), u1 = fmaf(d1, d1, dy2);
        const float  u2 = fmaf(d2, d2, dy2), u3 = fmaf(d3, d3, dy2);
        // l = e*log2(u) + c2 ; t = 2^l ; blob = 2^(-t)   (u==0 -> blob=1)
        const float  l0 = fmaf(p.z, LOG2F(u0), p.w);
        const float  l1 = fmaf(p.z, LOG2F(u1), p.w);
        const float  l2 = fmaf(p.z, LOG2F(u2), p.w);
        const float  l3 = fmaf(p.z, LOG2F(u3), p.w);
        const float  t0 = EXP2F(l0), t1 = EXP2F(l1);
        const float  t2 = EXP2F(l2), t3 = EXP2F(l3);
        const float  v0 = EXP2F(-t0), v1 = EXP2F(-t1);
        const float  v2 = EXP2F(-t2), v3 = EXP2F(-t3);
        v4f out_v; out_v.x = v0; out_v.y = v1; out_v.z = v2; out_v.w = v3;
        __builtin_nontemporal_store(out_v, bptr + (size_t)n * pstride);
        m0 = fmaxf(m0, v0 * inten);
        m1 = fmaxf(m1, v1 * inten);
        m2 = fmaxf(m2, v2 * inten);
        m3 = fmaxf(m3, v3 * inten);
    }

    v4f mm; mm.x = fminf(m0, 1.0f); mm.y = fminf(m1, 1.0f);
    mm.z = fminf(m2, 1.0f); mm.w = fminf(m3, 1.0f);
    __builtin_nontemporal_store(mm,
        (v4f*)(masks + (size_t)b3 * SZ * SZ + (size_t)y * SZ + x));
}

extern "C" void kernel_launch(void* const* d_in, const int* in_sizes, int n_in,
                              void* d_out, int out_size, void* d_ws, size_t ws_size,
                              hipStream_t stream) {
    const float* points      = (const float*)d_in[0];
    const float* sigmas      = (const float*)d_in[1];
    const float* exponents   = (const float*)d_in[2];
    const float* intensities = (const float*)d_in[3];
    const float* cam_s       = (const float*)d_in[4];
    const float* cam_e       = (const float*)d_in[5];
    const float* cam_i       = (const float*)d_in[6];

    float* out   = (float*)d_out;
    float* masks = out;                       // 6*256*256 = 393216 floats
    float* blobs = out + NB3 * SZ * SZ;       // 6*128*256*256 floats

    // 6 cams * 128 row-pairs = 768 blocks (3 per CU, balanced), 128 thr each
    hipLaunchKernelGGL(render_kernel, dim3(NB3 * (SZ / 2)), dim3(128), 0, stream,
                       points, sigmas, exponents, intensities,
                       cam_s, cam_e, cam_i, masks, blobs);
}